// Round 15
// baseline (207.015 us; speedup 1.0000x reference)
//
#include <hip/hip_runtime.h>

// Problem constants
#define BN   8
#define CC   256
#define HH   64
#define WW   64
#define GG   8
#define CG   32
#define KKK  9
#define OO   256
#define HW   (HH*WW)
#define NPAD 256
#define NOUT 216

// halo'd x_h geometry: pixel (y,x) lives at row y+2, col x+2 of a 68x68 grid
#define XH   68
#define XROW (XH*256)            // halves per pixel-row = 17408
#define XB   (XH*XH*256)         // halves per batch    = 1183744

// LDS-resident conv output: [216 ch][64 px] f32, row stride 68 (bank spread)
#define COS  68

typedef __attribute__((ext_vector_type(8))) _Float16 half8;
typedef __attribute__((ext_vector_type(4))) float f32x4;

union U4H8 { uint4 u; half8 h; };

#define LGKM0_BARRIER() do { \
    asm volatile("s_waitcnt lgkmcnt(0)" ::: "memory"); \
    __builtin_amdgcn_s_barrier(); \
    __builtin_amdgcn_sched_barrier(0); \
} while (0)

// ---------------------------------------------------------------------------
// prep_all: ONE launch doing all preprocessing (verified R14).
// ---------------------------------------------------------------------------
__global__ __launch_bounds__(256) void prep_all(
    const float* __restrict__ x, const float* __restrict__ w_out,
    const float* __restrict__ w_off, const float* __restrict__ b_off,
    const float* __restrict__ w_attn, const float* __restrict__ b_attn,
    _Float16* __restrict__ x_h, _Float16* __restrict__ wt3,
    _Float16* __restrict__ wt_conv, float* __restrict__ bias_c) {
    const int bid = blockIdx.x;
    const int t = threadIdx.x;

    if (bid < 512) {
        // ---- repack_x (interior) ----
        __shared__ _Float16 T[64][264];
        const int b = bid & 7, h = bid >> 3;
        const float* src = x + (((long)(b * 256 + t)) << 12) + h * 64;
        #pragma unroll
        for (int i = 0; i < 16; ++i) {
            float4 f = ((const float4*)src)[i];
            T[i * 4 + 0][t] = (_Float16)f.x;
            T[i * 4 + 1][t] = (_Float16)f.y;
            T[i * 4 + 2][t] = (_Float16)f.z;
            T[i * 4 + 3][t] = (_Float16)f.w;
        }
        __syncthreads();
        _Float16* dst = x_h + ((long)(b * XH + h + 2) * XH + 2) * 256;
        #pragma unroll
        for (int it = 0; it < 8; ++it) {
            int idx = it * 256 + t;
            int px = idx >> 5, ch = idx & 31;
            uint4 v = *(const uint4*)&T[px][ch * 8];
            *(uint4*)(dst + px * 256 + ch * 8) = v;
        }
    } else if (bid < 2816) {
        // ---- repack_w ----
        int idx = (bid - 512) * 256 + t;
        int e    = idx & 7;
        int lane = (idx >> 3) & 63;
        int ot   = (idx >> 9) & 15;
        int s    = idx >> 13;
        int kk = s % 9;
        int g  = s / 9;
        int oc = ot * 16 + (lane & 15);
        int cg = (lane >> 4) * 8 + e;
        wt3[idx] = (_Float16)w_out[oc * 2304 + (g * 32 + cg) * 9 + kk];
    } else if (bid < 5120) {
        // ---- repack_conv ----
        int idx = (bid - 2816) * 256 + t;
        int e    = idx & 7;
        int lane = (idx >> 3) & 63;
        int ot   = (idx >> 9) & 15;
        int gs   = idx >> 13;
        int tap = gs >> 3;
        int ch  = (gs & 7) * 32 + (lane >> 4) * 8 + e;
        int n   = ot * 16 + (lane & 15);
        float v = 0.f;
        if (n < 144)      v = w_off[(n * 256 + ch) * 9 + tap];
        else if (n < 216) v = w_attn[((n - 144) * 256 + ch) * 9 + tap];
        wt_conv[idx] = (_Float16)v;
        if (idx < 224) {
            float bv = 0.f;
            if (idx < 144)      bv = b_off[idx];
            else if (idx < 216) bv = b_attn[idx - 144];
            bias_c[idx] = bv;
        }
    } else {
        // ---- halo zero ----
        int gi = (bid - 5120) * 256 + t;
        int b    = gi / 16896;
        int r    = gi - b * 16896;
        int cell = r >> 5;
        int q    = r & 31;
        int row, col;
        if (cell < 272) {
            int rr = cell / 68;
            row = (rr < 2) ? rr : (rr + 64);
            col = cell - rr * 68;
        } else {
            int cc = cell - 272;
            row = 2 + (cc >> 2);
            int ci = cc & 3;
            col = (ci < 2) ? ci : (ci + 64);
        }
        _Float16* p = x_h + ((long)(b * XH + row) * XH + col) * 256 + q * 8;
        *(uint4*)p = make_uint4(0u, 0u, 0u, 0u);
    }
}

// ---------------------------------------------------------------------------
// coords on the zero-halo grid: NO masks, NO per-corner selects.
// ---------------------------------------------------------------------------
__device__ __forceinline__ void calc_coords(int h, int px, int ki, int kj,
    float dy, float dx, int& i00,
    float& u00, float& u01, float& u10, float& u11) {
    float py  = (float)(h - 1 + ki) + dy;
    float pxf = (float)(px - 1 + kj) + dx;
    float y0f = floorf(py), x0f = floorf(pxf);
    float wy1 = py - y0f, wx1 = pxf - x0f;
    float wy0 = 1.f - wy1, wx0 = 1.f - wx1;
    int y0 = min(max((int)y0f, -2), 64);
    int x0 = min(max((int)x0f, -2), 64);
    u00 = wy0 * wx0; u01 = wy0 * wx1;
    u10 = wy1 * wx0; u11 = wy1 * wx1;
    i00 = (y0 + 2) * XH + (x0 + 2);
}

// ---------------------------------------------------------------------------
// FUSED kernel: conv (implicit GEMM) -> LDS conv-output CO -> in-place
// softmax -> bilinear sample + modulation + MFMA contraction -> out.
// Grid 512 = (b,h); block 512 thr = 2 K-groups x 4 N-waves. Both phases use
// the R8-verified BK=32 split-K structure. CO[216][COS] f32 (58,752 B) +
// Ald[2][2][64][40] f16 (20,480 B) = 79,232 B LDS -> 2 blocks/CU.
// conv_buf never touches global memory.
// ---------------------------------------------------------------------------
__global__ __launch_bounds__(512, 4) void fused_mfma(
    const _Float16* __restrict__ x_h, const _Float16* __restrict__ wt_conv,
    const float* __restrict__ bias_c, const _Float16* __restrict__ wt3,
    const float* __restrict__ b_out, float* __restrict__ out) {
    __shared__ alignas(16) char smem[79232];
    float* CO = (float*)smem;                                   // [216][COS]
    _Float16 (*Ald)[2][64][40] = (_Float16 (*)[2][64][40])(smem + 58752);
    float* red = (float*)smem;                                  // aliases CO after last use

    const int bid = blockIdx.x;
    const int b = bid & 7, h = bid >> 3;
    const int t = threadIdx.x;
    const int lane = t & 63;
    const int wv = t >> 6;
    const int group = wv >> 2;      // K-half
    const int wg = wv & 3;          // N quarter
    const int tl = t & 255;
    const int px = tl >> 2, cq = tl & 3;
    const int gs0 = group * 36;
    const int colb = (lane >> 4) * 4;

    const _Float16* xb = x_h + (long)b * XB + cq * 8;

    // =========================== PHASE 1: conv ===========================
    {
        f32x4 acc[4][4];
        #pragma unroll
        for (int i = 0; i < 4; ++i)
            #pragma unroll
            for (int j = 0; j < 4; ++j) acc[i][j] = (f32x4){0.f, 0.f, 0.f, 0.f};

        const _Float16* wB = wt_conv + (long)(wg * 256 + lane) * 8;

        uint4 aR;
        uint4 bq0, bq1, bq2, bq3;

        // prologue: A(0) -> buf0; A(1) -> reg; B(0) -> regs
        {
            int gs = gs0;
            int tap = gs >> 3, cc = gs & 7;
            int y = h + tap / 3 + 1, xc = px + tap % 3 + 1;
            uint4 a0 = *(const uint4*)(xb + ((long)(y * XH + xc)) * 256 + cc * 32);
            *(uint4*)&Ald[group][0][px][cq * 8] = a0;
        }
        {
            int gs = gs0 + 1;
            int tap = gs >> 3, cc = gs & 7;
            int y = h + tap / 3 + 1, xc = px + tap % 3 + 1;
            aR = *(const uint4*)(xb + ((long)(y * XH + xc)) * 256 + cc * 32);
        }
        {
            const _Float16* wsB = wB + (long)gs0 * 8192;
            bq0 = *(const uint4*)(wsB);
            bq1 = *(const uint4*)(wsB + 512);
            bq2 = *(const uint4*)(wsB + 1024);
            bq3 = *(const uint4*)(wsB + 1536);
        }
        LGKM0_BARRIER();

        for (int s = 0; s < 36; ++s) {
            // (1) LDS write A(s+1)
            if (s < 35) {
                *(uint4*)&Ald[group][(s + 1) & 1][px][cq * 8] = aR;
            }
            // (2) issue A(s+2)
            if (s < 34) {
                int gs = gs0 + s + 2;
                int tap = gs >> 3, cc = gs & 7;
                int y = h + tap / 3 + 1, xc = px + tap % 3 + 1;
                aR = *(const uint4*)(xb + ((long)(y * XH + xc)) * 256 + cc * 32);
            }
            // (3) MFMA(s)
            {
                const int k0 = (lane >> 4) * 8;
                U4H8 b0, b1, b2, b3; b0.u = bq0; b1.u = bq1; b2.u = bq2; b3.u = bq3;
                #pragma unroll
                for (int mi = 0; mi < 4; ++mi) {
                    half8 a = *(const half8*)&Ald[group][s & 1][mi * 16 + (lane & 15)][k0];
                    acc[mi][0] = __builtin_amdgcn_mfma_f32_16x16x32_f16(a, b0.h, acc[mi][0], 0, 0, 0);
                    acc[mi][1] = __builtin_amdgcn_mfma_f32_16x16x32_f16(a, b1.h, acc[mi][1], 0, 0, 0);
                    acc[mi][2] = __builtin_amdgcn_mfma_f32_16x16x32_f16(a, b2.h, acc[mi][2], 0, 0, 0);
                    acc[mi][3] = __builtin_amdgcn_mfma_f32_16x16x32_f16(a, b3.h, acc[mi][3], 0, 0, 0);
                }
            }
            // (4) issue B(s+1)
            if (s < 35) {
                const _Float16* wsB = wB + (long)(gs0 + s + 1) * 8192;
                bq0 = *(const uint4*)(wsB);
                bq1 = *(const uint4*)(wsB + 512);
                bq2 = *(const uint4*)(wsB + 1024);
                bq3 = *(const uint4*)(wsB + 1536);
            }
            // (5) barrier
            LGKM0_BARRIER();
        }

        // split-K reduce into LDS CO (+bias)
        if (group == 1) {
            #pragma unroll
            for (int mi = 0; mi < 4; ++mi) {
                int px0 = mi * 16 + colb;
                #pragma unroll
                for (int j = 0; j < 4; ++j) {
                    int oc = wg * 64 + j * 16 + (lane & 15);
                    if (oc < NOUT) {
                        float4 v = make_float4(acc[mi][j][0], acc[mi][j][1],
                                               acc[mi][j][2], acc[mi][j][3]);
                        *(float4*)&CO[oc * COS + px0] = v;
                    }
                }
            }
        }
        __syncthreads();
        if (group == 0) {
            #pragma unroll
            for (int mi = 0; mi < 4; ++mi) {
                int px0 = mi * 16 + colb;
                #pragma unroll
                for (int j = 0; j < 4; ++j) {
                    int oc = wg * 64 + j * 16 + (lane & 15);
                    if (oc < NOUT) {
                        float bb = bias_c[oc];
                        float4 p = *(const float4*)&CO[oc * COS + px0];
                        float4 v = make_float4(p.x + acc[mi][j][0] + bb,
                                               p.y + acc[mi][j][1] + bb,
                                               p.z + acc[mi][j][2] + bb,
                                               p.w + acc[mi][j][3] + bb);
                        *(float4*)&CO[oc * COS + px0] = v;
                    }
                }
            }
        }
        __syncthreads();
    }

    // ===================== softmax in-place on CO[144..215] ==============
    {
        int ppx = t & 63, g = t >> 6;      // 512 threads = 8 g x 64 px
        float* ap = CO + (144 + g * 9) * COS + ppx;
        float v[9];
        float m = -1e30f;
        #pragma unroll
        for (int k = 0; k < 9; ++k) { v[k] = ap[k * COS]; m = fmaxf(m, v[k]); }
        float ssum = 0.f;
        #pragma unroll
        for (int k = 0; k < 9; ++k) { v[k] = __expf(v[k] - m); ssum += v[k]; }
        float inv = 1.f / ssum;
        #pragma unroll
        for (int k = 0; k < 9; ++k) ap[k * COS] = v[k] * inv;
    }
    __syncthreads();

    // =========================== PHASE 2: sample =========================
    {
        f32x4 acc[4][4];
        #pragma unroll
        for (int i = 0; i < 4; ++i)
            #pragma unroll
            for (int j = 0; j < 4; ++j) acc[i][j] = (f32x4){0.f, 0.f, 0.f, 0.f};

        const _Float16* xbase = xb;        // same x_h base (+cq*8)
        const _Float16* wB3 = wt3 + (long)(wg * 256 + lane) * 8;

        uint4 q00, q01, q10, q11;
        float u00, u01, u10, u11;
        uint4 bq0, bq1, bq2, bq3;

        // preamble: blend A(0) -> buf0; gathers(1); B(0)
        {
            float dy0 = CO[(2 * gs0) * COS + px], dx0 = CO[(2 * gs0 + 1) * COS + px];
            int i00;
            float v00, v01, v10, v11;
            calc_coords(h, px, 0, 0, dy0, dx0, i00, v00, v01, v10, v11);
            const _Float16* xg = xbase + (group * 4) * 32 + (long)i00 * 256;
            uint4 a00 = *(const uint4*)(xg);
            uint4 a01 = *(const uint4*)(xg + 256);
            uint4 a10 = *(const uint4*)(xg + XROW);
            uint4 a11 = *(const uint4*)(xg + XROW + 256);
            float av = CO[(144 + gs0) * COS + px];
            U4H8 h00, h01, h10, h11;
            h00.u = a00; h01.u = a01; h10.u = a10; h11.u = a11;
            half8 rr = h00.h * (_Float16)v00 + h01.h * (_Float16)v01
                     + h10.h * (_Float16)v10 + h11.h * (_Float16)v11;
            rr = rr * (_Float16)av;
            *(half8*)&Ald[group][0][px][cq * 8] = rr;
        }
        {
            float dy1 = CO[(2 * (gs0 + 1)) * COS + px];
            float dx1 = CO[(2 * (gs0 + 1) + 1) * COS + px];
            int i00;
            calc_coords(h, px, 0, 1, dy1, dx1, i00, u00, u01, u10, u11);
            const _Float16* xg = xbase + (group * 4) * 32 + (long)i00 * 256;
            q00 = *(const uint4*)(xg);
            q01 = *(const uint4*)(xg + 256);
            q10 = *(const uint4*)(xg + XROW);
            q11 = *(const uint4*)(xg + XROW + 256);
        }
        {
            const _Float16* wsB = wB3 + (long)gs0 * 8192;
            bq0 = *(const uint4*)(wsB);
            bq1 = *(const uint4*)(wsB + 512);
            bq2 = *(const uint4*)(wsB + 1024);
            bq3 = *(const uint4*)(wsB + 1536);
        }
        LGKM0_BARRIER();

        for (int s = 0; s < 36; ++s) {
            const int gs = gs0 + s;
            // (1) blend A(s+1); LDS write (other buffer)
            if (s < 35) {
                float av = CO[(144 + gs + 1) * COS + px];
                U4H8 a00, a01, a10, a11;
                a00.u = q00; a01.u = q01; a10.u = q10; a11.u = q11;
                half8 rr = a00.h * (_Float16)u00 + a01.h * (_Float16)u01
                         + a10.h * (_Float16)u10 + a11.h * (_Float16)u11;
                rr = rr * (_Float16)av;
                *(half8*)&Ald[group][(s + 1) & 1][px][cq * 8] = rr;
            }
            // (2) coords(s+2) from LDS dy/dx + issue gathers(s+2)
            if (s < 34) {
                int sn = s + 2;
                int g = group * 4 + sn / 9, kk = sn % 9;
                float dy = CO[(2 * (gs0 + sn)) * COS + px];
                float dx = CO[(2 * (gs0 + sn) + 1) * COS + px];
                int i00;
                calc_coords(h, px, kk / 3, kk % 3, dy, dx, i00, u00, u01, u10, u11);
                const _Float16* xg = xbase + g * 32 + (long)i00 * 256;
                q00 = *(const uint4*)(xg);
                q01 = *(const uint4*)(xg + 256);
                q10 = *(const uint4*)(xg + XROW);
                q11 = *(const uint4*)(xg + XROW + 256);
            }
            // (3) MFMA(s)
            {
                const int k0 = (lane >> 4) * 8;
                U4H8 b0, b1, b2, b3; b0.u = bq0; b1.u = bq1; b2.u = bq2; b3.u = bq3;
                #pragma unroll
                for (int mi = 0; mi < 4; ++mi) {
                    half8 a = *(const half8*)&Ald[group][s & 1][mi * 16 + (lane & 15)][k0];
                    acc[mi][0] = __builtin_amdgcn_mfma_f32_16x16x32_f16(a, b0.h, acc[mi][0], 0, 0, 0);
                    acc[mi][1] = __builtin_amdgcn_mfma_f32_16x16x32_f16(a, b1.h, acc[mi][1], 0, 0, 0);
                    acc[mi][2] = __builtin_amdgcn_mfma_f32_16x16x32_f16(a, b2.h, acc[mi][2], 0, 0, 0);
                    acc[mi][3] = __builtin_amdgcn_mfma_f32_16x16x32_f16(a, b3.h, acc[mi][3], 0, 0, 0);
                }
            }
            // (4) issue B(s+1)
            if (s < 35) {
                const _Float16* wsB = wB3 + (long)(gs + 1) * 8192;
                bq0 = *(const uint4*)(wsB);
                bq1 = *(const uint4*)(wsB + 512);
                bq2 = *(const uint4*)(wsB + 1024);
                bq3 = *(const uint4*)(wsB + 1536);
            }
            // (5) barrier
            LGKM0_BARRIER();
        }

        // cross-group K reduction via LDS (red aliases CO; CO is dead now)
        #pragma unroll
        for (int r = 0; r < 2; ++r) {
            __syncthreads();
            if (group == 1) {
                #pragma unroll
                for (int m2 = 0; m2 < 2; ++m2)
                    #pragma unroll
                    for (int j = 0; j < 4; ++j)
                        *(f32x4*)&red[tl * 36 + m2 * 16 + j * 4] = acc[r * 2 + m2][j];
            }
            __syncthreads();
            if (group == 0) {
                #pragma unroll
                for (int m2 = 0; m2 < 2; ++m2)
                    #pragma unroll
                    for (int j = 0; j < 4; ++j) {
                        f32x4 v = *(const f32x4*)&red[tl * 36 + m2 * 16 + j * 4];
                        acc[r * 2 + m2][j] += v;
                    }
            }
        }

        // epilogue (group 0 stores)
        if (group == 0) {
            #pragma unroll
            for (int mi = 0; mi < 4; ++mi) {
                int px0 = mi * 16 + colb;
                #pragma unroll
                for (int j = 0; j < 4; ++j) {
                    int oc = wg * 64 + j * 16 + (lane & 15);
                    float bb = b_out[oc];
                    float4 v = make_float4(acc[mi][j][0] + bb, acc[mi][j][1] + bb,
                                           acc[mi][j][2] + bb, acc[mi][j][3] + bb);
                    *(float4*)&out[((long)b * OO + oc) * HW + h * WW + px0] = v;
                }
            }
        }
    }
}

// ---------------------------------------------------------------------------
extern "C" void kernel_launch(void* const* d_in, const int* in_sizes, int n_in,
                              void* d_out, int out_size, void* d_ws, size_t ws_size,
                              hipStream_t stream) {
    const float* x      = (const float*)d_in[0];
    const float* w_off  = (const float*)d_in[1];
    const float* b_off  = (const float*)d_in[2];
    const float* w_attn = (const float*)d_in[3];
    const float* b_attn = (const float*)d_in[4];
    const float* w_out  = (const float*)d_in[5];
    const float* b_out  = (const float*)d_in[6];
    float* out = (float*)d_out;

    _Float16* x_h     = (_Float16*)d_ws;                    // 9,469,952 halves
    _Float16* wt3     = x_h + 9469952;                      // 589,824 halves
    _Float16* wt_conv = wt3 + 589824;                       // 589,824 halves
    float* bias_c     = (float*)(wt_conv + 589824);         // 224 floats

    // one merged prep launch: repack_x + repack_w + repack_conv + halo-zero
    prep_all<<<dim3(5648), dim3(256), 0, stream>>>(
        x, w_out, w_off, b_off, w_attn, b_attn, x_h, wt3, wt_conv, bias_c);

    // one fused conv+softmax+sample+gemm launch
    fused_mfma<<<dim3(512), dim3(512), 0, stream>>>(
        x_h, wt_conv, bias_c, wt3, b_out, out);
}